// Round 9
// baseline (273.093 us; speedup 1.0000x reference)
//
#include <hip/hip_runtime.h>
#include <hip/hip_bf16.h>

#define N_NODES 50000
#define N_EDGES 800000
#define NUM_GRAPHS 64
#define NBUCK 391       // ceil(50000/128)
#define SLAB 4096       // slab capacity per bucket (expected ~2048)

typedef __attribute__((ext_vector_type(8))) short short8;
typedef __attribute__((ext_vector_type(16))) float f32x16;

static __device__ __forceinline__ short f2bf(float f) {
    union { __hip_bfloat16 h; short s; } u;
    u.h = __float2bfloat16(f);
    return u.s;
}
static __device__ __forceinline__ unsigned short f2bfu(float f) {
    union { __hip_bfloat16 h; unsigned short s; } u;
    u.h = __float2bfloat16(f);
    return u.s;
}
static __device__ __forceinline__ float bflo(unsigned u) { return __uint_as_float(u << 16); }
static __device__ __forceinline__ float bfhi(unsigned u) { return __uint_as_float(u & 0xffff0000u); }

// Fused: x->bf16 convert (blocks 0..3124) | weight folds (3125..3380)
//        | init bcur slab cursors + zero pooled (3381..3414)
__global__ __launch_bounds__(256) void prep_kernel(
    const float* __restrict__ x, uint4* __restrict__ xb,
    const float* __restrict__ Wu1, const float* __restrict__ Wm1,
    const float* __restrict__ bm1, short* __restrict__ Wcatf1, float* __restrict__ c1,
    const float* __restrict__ Wu2, const float* __restrict__ Wm2,
    const float* __restrict__ bm2, short* __restrict__ Wcatf2, float* __restrict__ c2,
    int* __restrict__ bcur, float* __restrict__ pooled) {
    int bid = blockIdx.x, t = threadIdx.x;
    if (bid < 3125) {
        int i = bid * 256 + t;
        if (i < 800000) {
            const float4* p = (const float4*)(x + (size_t)i * 8);
            float4 f0 = p[0], f1 = p[1];
            uint4 r;
            r.x = ((unsigned)f2bfu(f0.y) << 16) | f2bfu(f0.x);
            r.y = ((unsigned)f2bfu(f0.w) << 16) | f2bfu(f0.z);
            r.z = ((unsigned)f2bfu(f1.y) << 16) | f2bfu(f1.x);
            r.w = ((unsigned)f2bfu(f1.w) << 16) | f2bfu(f1.z);
            xb[i] = r;
        }
    } else if (bid < 3381) {
        int lb = bid - 3125;
        int layer = lb >> 7;
        int o = lb & 127;
        int k = t;  // 0..255
        const float* Wu = layer ? Wu2 : Wu1;
        const float* Wm = layer ? Wm2 : Wm1;
        const float* bm = layer ? bm2 : bm1;
        short* Wcatf = layer ? Wcatf2 : Wcatf1;
        float* cvec = layer ? c2 : c1;
        float val;
        if (k < 128) {
            val = Wu[o * 256 + k];
        } else {
            int kk = k - 128;
            float s = 0.f;
            for (int j = 0; j < 128; ++j) s += Wu[o * 256 + 128 + j] * Wm[j * 128 + kk];
            val = s;
        }
        Wcatf[(((k >> 3) * 128) + o) * 8 + (k & 7)] = f2bf(val);
        if (k == 0) {
            float cs = 0.f;
            for (int j = 0; j < 128; ++j) cs += Wu[o * 256 + 128 + j] * bm[j];
            cvec[o] = cs;
        }
    } else {
        int i = (bid - 3381) * 256 + t;
        if (i < 512) bcur[i] = i * SLAB;            // slab cursor = slab base
        else if (i < 512 + 8192) pooled[i - 512] = 0.f;
    }
}

// pass A: bin edges by bucket through LDS; slab-allocate runs via bcur atomics
__global__ __launch_bounds__(1024) void binA_kernel(const int* __restrict__ row,
                                                    const int* __restrict__ col,
                                                    int* __restrict__ bcur,
                                                    unsigned* __restrict__ ebin, int E) {
    __shared__ int lcur[NBUCK];
    __shared__ int lscan[NBUCK];
    __shared__ int gbase[NBUCK];
    __shared__ int sscan[512];
    __shared__ unsigned stage[4096];
    int t = threadIdx.x;
    for (int i = t; i < NBUCK; i += 1024) lcur[i] = 0;
    __syncthreads();
    int e0 = blockIdx.x * 4096;
    unsigned pv[4];
    int pb[4], pr[4];
#pragma unroll
    for (int k = 0; k < 4; ++k) {
        int e = e0 + k * 1024 + t;
        if (e < E) {
            int r = row[e], c = col[e];
            pv[k] = ((unsigned)r << 16) | (unsigned)c;
            pb[k] = r >> 7;
            pr[k] = atomicAdd(&lcur[pb[k]], 1);
        } else {
            pb[k] = -1;
        }
    }
    __syncthreads();
    if (t < 512) sscan[t] = (t < NBUCK) ? lcur[t] : 0;
    __syncthreads();
    for (int o = 1; o < 512; o <<= 1) {
        int a = 0;
        if (t < 512 && t >= o) a = sscan[t - o];
        __syncthreads();
        if (t < 512) sscan[t] += a;
        __syncthreads();
    }
    if (t < NBUCK) lscan[t] = sscan[t] - lcur[t];
    __syncthreads();
    for (int i = t; i < NBUCK; i += 1024) {
        int c = lcur[i];
        gbase[i] = c ? atomicAdd(&bcur[i], c) : 0;
    }
#pragma unroll
    for (int k = 0; k < 4; ++k)
        if (pb[k] >= 0) stage[lscan[pb[k]] + pr[k]] = pv[k];
    __syncthreads();
    int total = E - e0;
    if (total > 4096) total = 4096;
    for (int idx = t; idx < total; idx += 1024) {
        unsigned v = stage[idx];
        int b = v >> 23;
        ebin[gbase[b] + (idx - lscan[b])] = v;
    }
}

// pass B: per bucket slab, build csr segment + hist + off entirely in LDS
__global__ __launch_bounds__(256) void binB_kernel(const unsigned* __restrict__ ebin,
                                                   const int* __restrict__ bcur,
                                                   int* __restrict__ csr,
                                                   int* __restrict__ hist,
                                                   int* __restrict__ off, int N) {
    __shared__ int lcnt[128];
    __shared__ int loff[128];
    __shared__ int lcur2[128];
    __shared__ int sscan[128];
    __shared__ unsigned short stage[SLAB];
    int b = blockIdx.x, t = threadIdx.x;
    int base = b * SLAB;
    int n = bcur[b] - base;
    if (n > SLAB) n = SLAB;  // safety clamp
    if (t < 128) lcnt[t] = 0;
    __syncthreads();
    for (int idx = t; idx < n; idx += 256) {
        unsigned v = ebin[base + idx];
        atomicAdd(&lcnt[(v >> 16) & 127], 1);
    }
    __syncthreads();
    if (t < 128) sscan[t] = lcnt[t];
    __syncthreads();
    for (int o = 1; o < 128; o <<= 1) {
        int a = 0;
        if (t < 128 && t >= o) a = sscan[t - o];
        __syncthreads();
        if (t < 128) sscan[t] += a;
        __syncthreads();
    }
    if (t < 128) {
        loff[t] = sscan[t] - lcnt[t];
        lcur2[t] = sscan[t] - lcnt[t];
    }
    __syncthreads();
    for (int idx = t; idx < n; idx += 256) {
        unsigned v = ebin[base + idx];
        int lr = (v >> 16) & 127;
        int pos = atomicAdd(&lcur2[lr], 1);
        stage[pos] = (unsigned short)(v & 0xffffu);
    }
    __syncthreads();
    for (int idx = t; idx < n; idx += 256) csr[base + idx] = (int)stage[idx];
    int r0 = b * 128;
    if (t < 128 && r0 + t < N) {
        hist[r0 + t] = lcnt[t];
        off[r0 + t] = base + loff[t];
    }
}

// Channel-sliced gather: pass p reads only cols [32p,32p+32) of each row (64B = 1 line),
// so the per-pass working set (3.2MB) is L2-resident per XCD. Pass = OUTER loop;
// persistent grid so concurrent waves stay in the same pass. csr/agg traffic bypasses
// L2 via nontemporal ops to protect the resident slice.
__global__ __launch_bounds__(256) void gather_kernel(const unsigned* __restrict__ src,
                                                     const int* __restrict__ off,
                                                     const int* __restrict__ hist,
                                                     const int* __restrict__ csr,
                                                     unsigned* __restrict__ aggb, int N) {
    const int wave = threadIdx.x >> 6, lane = threadIdx.x & 63;
    const int grp = lane >> 4, sub = lane & 15;
    const int wid0 = blockIdx.x * 4 + wave;
    const int wstride = gridDim.x * 4;
#pragma unroll
    for (int pass = 0; pass < 4; ++pass) {
        const unsigned* sp = src + pass * 16 + sub;
        for (int n = wid0; n < N; n += wstride) {
            int s = off[n];
            int e = s + hist[n];
            float a0 = 0.f, a1 = 0.f;
#pragma unroll 4
            for (int i = s + grp; i < e; i += 4) {
                int c = __builtin_nontemporal_load(csr + i);
                unsigned v = sp[(size_t)c * 64];
                a0 += bflo(v);
                a1 += bfhi(v);
            }
            a0 += __shfl_xor(a0, 16); a1 += __shfl_xor(a1, 16);
            a0 += __shfl_xor(a0, 32); a1 += __shfl_xor(a1, 32);
            if (grp == 0) {
                unsigned r = ((unsigned)f2bfu(a1) << 16) | f2bfu(a0);
                __builtin_nontemporal_store(r, aggb + (size_t)n * 64 + pass * 16 + sub);
            }
        }
    }
}

// h = relu([xin|agg] @ Wcat^T + deg*c + bu).  512 thr = 8 waves; block = 256 nodes.
template <int POOL>
__global__ __launch_bounds__(512) void update_kernel(
    const void* __restrict__ xin_, const unsigned int* __restrict__ aggb,
    const int* __restrict__ hist, const float* __restrict__ cvec,
    const float* __restrict__ bupd, const short* __restrict__ Wcatf,
    unsigned int* __restrict__ houtb, float* __restrict__ pooled,
    const int* __restrict__ batch, int N) {
    __shared__ short lds_s[32768];  // 64KB
    const int tid = threadIdx.x;
    const int wave = tid >> 6, lane = tid & 63;
    const int l31 = lane & 31, hi = lane >> 5;

    {  // stage B: linear 64KB copy
        const uint4* g = (const uint4*)Wcatf;
        uint4* l4 = (uint4*)lds_s;
#pragma unroll
        for (int j = 0; j < 8; ++j) l4[j * 512 + tid] = g[j * 512 + tid];
    }
    __syncthreads();

    const int m0 = blockIdx.x * 256 + wave * 32;
    int nr = m0 + l31;
    if (nr >= N) nr = N - 1;
    f32x16 acc[4] = {};
#pragma unroll
    for (int step = 0; step < 16; ++step) {
        short8 a;
        if (step < 8) {
            a = *(const short8*)((const short*)xin_ + (size_t)nr * 128 + step * 16 + hi * 8);
        } else {
            a = *(const short8*)((const short*)aggb + (size_t)nr * 128 + (step - 8) * 16 + hi * 8);
        }
#pragma unroll
        for (int ct = 0; ct < 4; ++ct) {
            const short8 b = *(const short8*)(lds_s + (((step * 2 + hi) * 128) + ct * 32 + l31) * 8);
            acc[ct] = __builtin_amdgcn_mfma_f32_32x32x16_bf16(a, b, acc[ct], 0, 0, 0);
        }
    }
    __syncthreads();  // B dead; LDS becomes transpose buffer

    float dv[16];
#pragma unroll
    for (int r = 0; r < 16; ++r) {
        int row = (r & 3) + 8 * (r >> 2) + 4 * hi;
        int node = m0 + row;
        if (node >= N) node = N - 1;
        dv[r] = (float)hist[node];
    }
    short* tp = lds_s + wave * 4096;  // [32][128] bf16 per wave
#pragma unroll
    for (int ct = 0; ct < 4; ++ct) {
        int o = ct * 32 + l31;
        float co = cvec[o], bo = bupd[o];
#pragma unroll
        for (int r = 0; r < 16; ++r) {
            int row = (r & 3) + 8 * (r >> 2) + 4 * hi;
            float v = fmaxf(acc[ct][r] + dv[r] * co + bo, 0.f);
            tp[row * 128 + o] = f2bf(v);
        }
    }
    __syncthreads();

    if (POOL == 0) {
        const uint4* l4 = (const uint4*)tp;
#pragma unroll
        for (int j = 0; j < 8; ++j) {
            int node = m0 + j * 4 + (lane >> 4);
            if (node < N)
                ((uint4*)houtb)[(size_t)m0 * 16 + j * 64 + lane] = l4[j * 64 + lane];
        }
    } else {
        // block-local segmented pool over sorted batch
        int c = tid & 127, seg = tid >> 7;
        int base = blockIdx.x * 256 + seg * 64;
        float s = 0.f;
        int gprev = -1;
        for (int i = 0; i < 64; ++i) {
            int node = base + i;
            if (node >= N) break;
            int g = batch[node];
            if (g != gprev) {
                if (gprev >= 0) atomicAdd(&pooled[gprev * 128 + c], s);
                s = 0.f;
                gprev = g;
            }
            unsigned u = (unsigned short)lds_s[(seg * 64 + i) * 128 + c];
            s += __uint_as_float(u << 16);
        }
        if (gprev >= 0) atomicAdd(&pooled[gprev * 128 + c], s);
    }
}

// out[g] = (pooled[g]/count(g)) @ Wcls^T + bcls; count via binary search on sorted batch
__global__ void final_kernel(const float* __restrict__ pooled, const int* __restrict__ batch,
                             const float* __restrict__ Wcls, const float* __restrict__ bcls,
                             float* __restrict__ out, int N) {
    __shared__ float sh[128];
    __shared__ int cntsh;
    int g = blockIdx.x;
    int t = threadIdx.x;
    if (t == 0) {
        int lo = 0, hi = N;
        while (lo < hi) { int mid = (lo + hi) >> 1; if (batch[mid] < g) lo = mid + 1; else hi = mid; }
        int start = lo;
        lo = 0; hi = N;
        while (lo < hi) { int mid = (lo + hi) >> 1; if (batch[mid] < g + 1) lo = mid + 1; else hi = mid; }
        cntsh = lo - start;
    }
    __syncthreads();
    float c = (cntsh > 0) ? (float)cntsh : 1.f;
    sh[t] = pooled[g * 128 + t] / c;
    __syncthreads();
    if (t < 10) {
        float s = bcls[t];
        for (int i = 0; i < 128; ++i) s += sh[i] * Wcls[t * 128 + i];
        out[g * 10 + t] = s;
    }
}

extern "C" void kernel_launch(void* const* d_in, const int* in_sizes, int n_in,
                              void* d_out, int out_size, void* d_ws, size_t ws_size,
                              hipStream_t stream) {
    const float* x = (const float*)d_in[0];
    const int* ei = (const int*)d_in[1];
    const int* batch = (const int*)d_in[2];
    const float* Wm1 = (const float*)d_in[3];
    const float* bm1 = (const float*)d_in[4];
    const float* Wu1 = (const float*)d_in[5];
    const float* bu1 = (const float*)d_in[6];
    const float* Wm2 = (const float*)d_in[7];
    const float* bm2 = (const float*)d_in[8];
    const float* Wu2 = (const float*)d_in[9];
    const float* bu2 = (const float*)d_in[10];
    const float* Wcls = (const float*)d_in[11];
    const float* bcls = (const float*)d_in[12];
    float* out = (float*)d_out;

    const int N = N_NODES, E = N_EDGES;
    const int* row = ei;
    const int* col = ei + E;
    const int EB = (E + 4095) / 4096;  // 196 binning blocks
    const int UB = (N + 255) / 256;    // 196 update blocks
    const int GB = 2048;               // persistent gather grid (8 blocks/CU)

    // workspace layout (int units from base)
    int* bcur = (int*)d_ws;                        // 512
    float* pooled = (float*)(bcur + 512);          // 8192
    int* hist = (int*)(pooled + 8192);             // 50000
    int* off = hist + 50000;                       // 50000
    unsigned* ebin = (unsigned*)(off + 50000);     // NBUCK*SLAB = 1,601,536
    int* csr = (int*)(ebin + NBUCK * SLAB);        // 1,601,536
    unsigned* aggb = (unsigned*)(csr + NBUCK * SLAB);  // 3,200,000
    unsigned* h1b = aggb + 3200000;                // 3,200,000
    unsigned* xb = h1b + 3200000;                  // 3,200,000
    float* c1 = (float*)(xb + 3200000);            // 128
    float* c2 = c1 + 128;                          // 128
    short* Wcatf1 = (short*)(c2 + 128);            // 32768 shorts
    short* Wcatf2 = Wcatf1 + 32768;                // 32768 shorts

    prep_kernel<<<3415, 256, 0, stream>>>(x, (uint4*)xb, Wu1, Wm1, bm1, Wcatf1, c1,
                                          Wu2, Wm2, bm2, Wcatf2, c2, bcur, pooled);
    binA_kernel<<<EB, 1024, 0, stream>>>(row, col, bcur, ebin, E);
    binB_kernel<<<NBUCK, 256, 0, stream>>>(ebin, bcur, csr, hist, off, N);

    // layer 1
    gather_kernel<<<GB, 256, 0, stream>>>(xb, off, hist, csr, aggb, N);
    update_kernel<0><<<UB, 512, 0, stream>>>(xb, aggb, hist, c1, bu1, Wcatf1,
                                             h1b, nullptr, nullptr, N);
    // layer 2
    gather_kernel<<<GB, 256, 0, stream>>>(h1b, off, hist, csr, aggb, N);
    update_kernel<1><<<UB, 512, 0, stream>>>(h1b, aggb, hist, c2, bu2, Wcatf2,
                                             nullptr, pooled, batch, N);

    final_kernel<<<NUM_GRAPHS, 128, 0, stream>>>(pooled, batch, Wcls, bcls, out, N);
}

// Round 10
// 134.918 us; speedup vs baseline: 2.0241x; 2.0241x over previous
//
#include <hip/hip_runtime.h>
#include <hip/hip_bf16.h>

#define N_NODES 50000
#define N_EDGES 800000
#define NUM_GRAPHS 64
#define NBUCK 391       // ceil(50000/128)
#define SLAB 4096       // slab capacity per bucket (expected ~2048)

typedef __attribute__((ext_vector_type(8))) short short8;
typedef __attribute__((ext_vector_type(16))) float f32x16;

static __device__ __forceinline__ short f2bf(float f) {
    union { __hip_bfloat16 h; short s; } u;
    u.h = __float2bfloat16(f);
    return u.s;
}
static __device__ __forceinline__ unsigned short f2bfu(float f) {
    union { __hip_bfloat16 h; unsigned short s; } u;
    u.h = __float2bfloat16(f);
    return u.s;
}
static __device__ __forceinline__ float bflo(unsigned u) { return __uint_as_float(u << 16); }
static __device__ __forceinline__ float bfhi(unsigned u) { return __uint_as_float(u & 0xffff0000u); }

// Fused: x->bf16 convert (blocks 0..3124) | weight folds (3125..3380)
//        | init bcur slab cursors + zero pooled (3381..3414)
__global__ __launch_bounds__(256) void prep_kernel(
    const float* __restrict__ x, uint4* __restrict__ xb,
    const float* __restrict__ Wu1, const float* __restrict__ Wm1,
    const float* __restrict__ bm1, short* __restrict__ Wcatf1, float* __restrict__ c1,
    const float* __restrict__ Wu2, const float* __restrict__ Wm2,
    const float* __restrict__ bm2, short* __restrict__ Wcatf2, float* __restrict__ c2,
    int* __restrict__ bcur, float* __restrict__ pooled) {
    int bid = blockIdx.x, t = threadIdx.x;
    if (bid < 3125) {
        int i = bid * 256 + t;
        if (i < 800000) {
            const float4* p = (const float4*)(x + (size_t)i * 8);
            float4 f0 = p[0], f1 = p[1];
            uint4 r;
            r.x = ((unsigned)f2bfu(f0.y) << 16) | f2bfu(f0.x);
            r.y = ((unsigned)f2bfu(f0.w) << 16) | f2bfu(f0.z);
            r.z = ((unsigned)f2bfu(f1.y) << 16) | f2bfu(f1.x);
            r.w = ((unsigned)f2bfu(f1.w) << 16) | f2bfu(f1.z);
            xb[i] = r;
        }
    } else if (bid < 3381) {
        int lb = bid - 3125;
        int layer = lb >> 7;
        int o = lb & 127;
        int k = t;  // 0..255
        const float* Wu = layer ? Wu2 : Wu1;
        const float* Wm = layer ? Wm2 : Wm1;
        const float* bm = layer ? bm2 : bm1;
        short* Wcatf = layer ? Wcatf2 : Wcatf1;
        float* cvec = layer ? c2 : c1;
        float val;
        if (k < 128) {
            val = Wu[o * 256 + k];
        } else {
            int kk = k - 128;
            float s = 0.f;
            for (int j = 0; j < 128; ++j) s += Wu[o * 256 + 128 + j] * Wm[j * 128 + kk];
            val = s;
        }
        Wcatf[(((k >> 3) * 128) + o) * 8 + (k & 7)] = f2bf(val);
        if (k == 0) {
            float cs = 0.f;
            for (int j = 0; j < 128; ++j) cs += Wu[o * 256 + 128 + j] * bm[j];
            cvec[o] = cs;
        }
    } else {
        int i = (bid - 3381) * 256 + t;
        if (i < 512) bcur[i] = i * SLAB;            // slab cursor = slab base
        else if (i < 512 + 8192) pooled[i - 512] = 0.f;
    }
}

// pass A: bin edges by bucket through LDS; slab-allocate runs via bcur atomics.
// 8192 edges/block -> ~21-edge (84B) runs per bucket, half the scan overhead of 4096.
__global__ __launch_bounds__(1024) void binA_kernel(const int* __restrict__ row,
                                                    const int* __restrict__ col,
                                                    int* __restrict__ bcur,
                                                    unsigned* __restrict__ ebin, int E) {
    __shared__ int lcur[NBUCK];
    __shared__ int lscan[NBUCK];
    __shared__ int gbase[NBUCK];
    __shared__ int sscan[512];
    __shared__ unsigned stage[8192];
    int t = threadIdx.x;
    for (int i = t; i < NBUCK; i += 1024) lcur[i] = 0;
    __syncthreads();
    int e0 = blockIdx.x * 8192;
    unsigned pv[8];
    int pb[8], pr[8];
#pragma unroll
    for (int k = 0; k < 8; ++k) {
        int e = e0 + k * 1024 + t;
        if (e < E) {
            int r = row[e], c = col[e];
            pv[k] = ((unsigned)r << 16) | (unsigned)c;
            pb[k] = r >> 7;
            pr[k] = atomicAdd(&lcur[pb[k]], 1);
        } else {
            pb[k] = -1;
        }
    }
    __syncthreads();
    if (t < 512) sscan[t] = (t < NBUCK) ? lcur[t] : 0;
    __syncthreads();
    for (int o = 1; o < 512; o <<= 1) {
        int a = 0;
        if (t < 512 && t >= o) a = sscan[t - o];
        __syncthreads();
        if (t < 512) sscan[t] += a;
        __syncthreads();
    }
    if (t < NBUCK) lscan[t] = sscan[t] - lcur[t];
    __syncthreads();
    for (int i = t; i < NBUCK; i += 1024) {
        int c = lcur[i];
        gbase[i] = c ? atomicAdd(&bcur[i], c) : 0;
    }
#pragma unroll
    for (int k = 0; k < 8; ++k)
        if (pb[k] >= 0) stage[lscan[pb[k]] + pr[k]] = pv[k];
    __syncthreads();
    int total = E - e0;
    if (total > 8192) total = 8192;
    for (int idx = t; idx < total; idx += 1024) {
        unsigned v = stage[idx];
        int b = v >> 23;
        ebin[gbase[b] + (idx - lscan[b])] = v;
    }
}

// pass B: per bucket slab, build csr segment + hist + off entirely in LDS
__global__ __launch_bounds__(256) void binB_kernel(const unsigned* __restrict__ ebin,
                                                   const int* __restrict__ bcur,
                                                   int* __restrict__ csr,
                                                   int* __restrict__ hist,
                                                   int* __restrict__ off, int N) {
    __shared__ int lcnt[128];
    __shared__ int loff[128];
    __shared__ int lcur2[128];
    __shared__ int sscan[128];
    __shared__ unsigned short stage[SLAB];
    int b = blockIdx.x, t = threadIdx.x;
    int base = b * SLAB;
    int n = bcur[b] - base;
    if (n > SLAB) n = SLAB;  // safety clamp
    if (t < 128) lcnt[t] = 0;
    __syncthreads();
    for (int idx = t; idx < n; idx += 256) {
        unsigned v = ebin[base + idx];
        atomicAdd(&lcnt[(v >> 16) & 127], 1);
    }
    __syncthreads();
    if (t < 128) sscan[t] = lcnt[t];
    __syncthreads();
    for (int o = 1; o < 128; o <<= 1) {
        int a = 0;
        if (t < 128 && t >= o) a = sscan[t - o];
        __syncthreads();
        if (t < 128) sscan[t] += a;
        __syncthreads();
    }
    if (t < 128) {
        loff[t] = sscan[t] - lcnt[t];
        lcur2[t] = sscan[t] - lcnt[t];
    }
    __syncthreads();
    for (int idx = t; idx < n; idx += 256) {
        unsigned v = ebin[base + idx];
        int lr = (v >> 16) & 127;
        int pos = atomicAdd(&lcur2[lr], 1);
        stage[pos] = (unsigned short)(v & 0xffffu);
    }
    __syncthreads();
    for (int idx = t; idx < n; idx += 256) csr[base + idx] = (int)stage[idx];
    int r0 = b * 128;
    if (t < 128 && r0 + t < N) {
        hist[r0 + t] = lcnt[t];
        off[r0 + t] = base + loff[t];
    }
}

// agg[n] = sum of src rows (bf16) over csr neighbors. One wave per node.
// 16-lane group strides its own neighbors; group lanes share one csr[i] (HW broadcast).
__global__ __launch_bounds__(256) void gather_kernel(const unsigned short* __restrict__ src,
                                                     const int* __restrict__ off,
                                                     const int* __restrict__ hist,
                                                     const int* __restrict__ csr,
                                                     unsigned int* __restrict__ aggb, int N) {
    int wave = threadIdx.x >> 6, lane = threadIdx.x & 63;
    int n = blockIdx.x * 4 + wave;
    if (n >= N) return;
    int s = off[n];
    int e = s + hist[n];
    int grp = lane >> 4, sub = lane & 15;
    float a0 = 0.f, a1 = 0.f, a2 = 0.f, a3 = 0.f, a4 = 0.f, a5 = 0.f, a6 = 0.f, a7 = 0.f;
#pragma unroll 4
    for (int i = s + grp; i < e; i += 4) {
        int c = csr[i];
        uint4 v = *(const uint4*)(src + (size_t)c * 128 + sub * 8);
        a0 += bflo(v.x); a1 += bfhi(v.x);
        a2 += bflo(v.y); a3 += bfhi(v.y);
        a4 += bflo(v.z); a5 += bfhi(v.z);
        a6 += bflo(v.w); a7 += bfhi(v.w);
    }
#pragma unroll
    for (int mk = 16; mk <= 32; mk <<= 1) {
        a0 += __shfl_xor(a0, mk); a1 += __shfl_xor(a1, mk);
        a2 += __shfl_xor(a2, mk); a3 += __shfl_xor(a3, mk);
        a4 += __shfl_xor(a4, mk); a5 += __shfl_xor(a5, mk);
        a6 += __shfl_xor(a6, mk); a7 += __shfl_xor(a7, mk);
    }
    if (grp == 0) {
        uint4 r;
        r.x = ((unsigned)f2bfu(a1) << 16) | f2bfu(a0);
        r.y = ((unsigned)f2bfu(a3) << 16) | f2bfu(a2);
        r.z = ((unsigned)f2bfu(a5) << 16) | f2bfu(a4);
        r.w = ((unsigned)f2bfu(a7) << 16) | f2bfu(a6);
        ((uint4*)aggb)[(size_t)n * 16 + sub] = r;
    }
}

// h = relu([xin|agg] @ Wcat^T + deg*c + bu).  512 thr = 8 waves; block = 256 nodes.
template <int POOL>
__global__ __launch_bounds__(512) void update_kernel(
    const void* __restrict__ xin_, const unsigned int* __restrict__ aggb,
    const int* __restrict__ hist, const float* __restrict__ cvec,
    const float* __restrict__ bupd, const short* __restrict__ Wcatf,
    unsigned int* __restrict__ houtb, float* __restrict__ pooled,
    const int* __restrict__ batch, int N) {
    __shared__ short lds_s[32768];  // 64KB
    const int tid = threadIdx.x;
    const int wave = tid >> 6, lane = tid & 63;
    const int l31 = lane & 31, hi = lane >> 5;

    {  // stage B: linear 64KB copy
        const uint4* g = (const uint4*)Wcatf;
        uint4* l4 = (uint4*)lds_s;
#pragma unroll
        for (int j = 0; j < 8; ++j) l4[j * 512 + tid] = g[j * 512 + tid];
    }
    __syncthreads();

    const int m0 = blockIdx.x * 256 + wave * 32;
    int nr = m0 + l31;
    if (nr >= N) nr = N - 1;
    f32x16 acc[4] = {};
#pragma unroll
    for (int step = 0; step < 16; ++step) {
        short8 a;
        if (step < 8) {
            a = *(const short8*)((const short*)xin_ + (size_t)nr * 128 + step * 16 + hi * 8);
        } else {
            a = *(const short8*)((const short*)aggb + (size_t)nr * 128 + (step - 8) * 16 + hi * 8);
        }
#pragma unroll
        for (int ct = 0; ct < 4; ++ct) {
            const short8 b = *(const short8*)(lds_s + (((step * 2 + hi) * 128) + ct * 32 + l31) * 8);
            acc[ct] = __builtin_amdgcn_mfma_f32_32x32x16_bf16(a, b, acc[ct], 0, 0, 0);
        }
    }
    __syncthreads();  // B dead; LDS becomes transpose buffer

    float dv[16];
#pragma unroll
    for (int r = 0; r < 16; ++r) {
        int row = (r & 3) + 8 * (r >> 2) + 4 * hi;
        int node = m0 + row;
        if (node >= N) node = N - 1;
        dv[r] = (float)hist[node];
    }
    short* tp = lds_s + wave * 4096;  // [32][128] bf16 per wave
#pragma unroll
    for (int ct = 0; ct < 4; ++ct) {
        int o = ct * 32 + l31;
        float co = cvec[o], bo = bupd[o];
#pragma unroll
        for (int r = 0; r < 16; ++r) {
            int row = (r & 3) + 8 * (r >> 2) + 4 * hi;
            float v = fmaxf(acc[ct][r] + dv[r] * co + bo, 0.f);
            tp[row * 128 + o] = f2bf(v);
        }
    }
    __syncthreads();

    if (POOL == 0) {
        const uint4* l4 = (const uint4*)tp;
#pragma unroll
        for (int j = 0; j < 8; ++j) {
            int node = m0 + j * 4 + (lane >> 4);
            if (node < N)
                ((uint4*)houtb)[(size_t)m0 * 16 + j * 64 + lane] = l4[j * 64 + lane];
        }
    } else {
        // block-local segmented pool over sorted batch
        int c = tid & 127, seg = tid >> 7;
        int base = blockIdx.x * 256 + seg * 64;
        float s = 0.f;
        int gprev = -1;
        for (int i = 0; i < 64; ++i) {
            int node = base + i;
            if (node >= N) break;
            int g = batch[node];
            if (g != gprev) {
                if (gprev >= 0) atomicAdd(&pooled[gprev * 128 + c], s);
                s = 0.f;
                gprev = g;
            }
            unsigned u = (unsigned short)lds_s[(seg * 64 + i) * 128 + c];
            s += __uint_as_float(u << 16);
        }
        if (gprev >= 0) atomicAdd(&pooled[gprev * 128 + c], s);
    }
}

// out[g] = (pooled[g]/count(g)) @ Wcls^T + bcls; count via binary search on sorted batch
__global__ void final_kernel(const float* __restrict__ pooled, const int* __restrict__ batch,
                             const float* __restrict__ Wcls, const float* __restrict__ bcls,
                             float* __restrict__ out, int N) {
    __shared__ float sh[128];
    __shared__ int cntsh;
    int g = blockIdx.x;
    int t = threadIdx.x;
    if (t == 0) {
        int lo = 0, hi = N;
        while (lo < hi) { int mid = (lo + hi) >> 1; if (batch[mid] < g) lo = mid + 1; else hi = mid; }
        int start = lo;
        lo = 0; hi = N;
        while (lo < hi) { int mid = (lo + hi) >> 1; if (batch[mid] < g + 1) lo = mid + 1; else hi = mid; }
        cntsh = lo - start;
    }
    __syncthreads();
    float c = (cntsh > 0) ? (float)cntsh : 1.f;
    sh[t] = pooled[g * 128 + t] / c;
    __syncthreads();
    if (t < 10) {
        float s = bcls[t];
        for (int i = 0; i < 128; ++i) s += sh[i] * Wcls[t * 128 + i];
        out[g * 10 + t] = s;
    }
}

extern "C" void kernel_launch(void* const* d_in, const int* in_sizes, int n_in,
                              void* d_out, int out_size, void* d_ws, size_t ws_size,
                              hipStream_t stream) {
    const float* x = (const float*)d_in[0];
    const int* ei = (const int*)d_in[1];
    const int* batch = (const int*)d_in[2];
    const float* Wm1 = (const float*)d_in[3];
    const float* bm1 = (const float*)d_in[4];
    const float* Wu1 = (const float*)d_in[5];
    const float* bu1 = (const float*)d_in[6];
    const float* Wm2 = (const float*)d_in[7];
    const float* bm2 = (const float*)d_in[8];
    const float* Wu2 = (const float*)d_in[9];
    const float* bu2 = (const float*)d_in[10];
    const float* Wcls = (const float*)d_in[11];
    const float* bcls = (const float*)d_in[12];
    float* out = (float*)d_out;

    const int N = N_NODES, E = N_EDGES;
    const int* row = ei;
    const int* col = ei + E;
    const int EB = (E + 8191) / 8192;  // 98 binning blocks
    const int UB = (N + 255) / 256;    // 196 update blocks
    const int GB = (N + 3) / 4;        // 12500 gather blocks

    // workspace layout (int units from base)
    int* bcur = (int*)d_ws;                        // 512
    float* pooled = (float*)(bcur + 512);          // 8192
    int* hist = (int*)(pooled + 8192);             // 50000
    int* off = hist + 50000;                       // 50000
    unsigned* ebin = (unsigned*)(off + 50000);     // NBUCK*SLAB = 1,601,536
    int* csr = (int*)(ebin + NBUCK * SLAB);        // 1,601,536
    unsigned* aggb = (unsigned*)(csr + NBUCK * SLAB);  // 3,200,000
    unsigned* h1b = aggb + 3200000;                // 3,200,000
    unsigned* xb = h1b + 3200000;                  // 3,200,000
    float* c1 = (float*)(xb + 3200000);            // 128
    float* c2 = c1 + 128;                          // 128
    short* Wcatf1 = (short*)(c2 + 128);            // 32768 shorts
    short* Wcatf2 = Wcatf1 + 32768;                // 32768 shorts

    prep_kernel<<<3415, 256, 0, stream>>>(x, (uint4*)xb, Wu1, Wm1, bm1, Wcatf1, c1,
                                          Wu2, Wm2, bm2, Wcatf2, c2, bcur, pooled);
    binA_kernel<<<EB, 1024, 0, stream>>>(row, col, bcur, ebin, E);
    binB_kernel<<<NBUCK, 256, 0, stream>>>(ebin, bcur, csr, hist, off, N);

    // layer 1
    gather_kernel<<<GB, 256, 0, stream>>>((const unsigned short*)xb, off, hist,
                                          csr, aggb, N);
    update_kernel<0><<<UB, 512, 0, stream>>>(xb, aggb, hist, c1, bu1, Wcatf1,
                                             h1b, nullptr, nullptr, N);
    // layer 2
    gather_kernel<<<GB, 256, 0, stream>>>((const unsigned short*)h1b, off, hist,
                                          csr, aggb, N);
    update_kernel<1><<<UB, 512, 0, stream>>>(h1b, aggb, hist, c2, bu2, Wcatf2,
                                             nullptr, pooled, batch, N);

    final_kernel<<<NUM_GRAPHS, 128, 0, stream>>>(pooled, batch, Wcls, bcls, out, N);
}

// Round 11
// 127.207 us; speedup vs baseline: 2.1468x; 1.0606x over previous
//
#include <hip/hip_runtime.h>
#include <hip/hip_bf16.h>

#define N_NODES 50000
#define N_EDGES 800000
#define NUM_GRAPHS 64
#define NBUCK 391       // ceil(50000/128)
#define SLAB 4096       // slab capacity per bucket (expected ~2048)

typedef __attribute__((ext_vector_type(8))) short short8;
typedef __attribute__((ext_vector_type(16))) float f32x16;

static __device__ __forceinline__ short f2bf(float f) {
    union { __hip_bfloat16 h; short s; } u;
    u.h = __float2bfloat16(f);
    return u.s;
}
static __device__ __forceinline__ unsigned short f2bfu(float f) {
    union { __hip_bfloat16 h; unsigned short s; } u;
    u.h = __float2bfloat16(f);
    return u.s;
}
static __device__ __forceinline__ float bflo(unsigned u) { return __uint_as_float(u << 16); }
static __device__ __forceinline__ float bfhi(unsigned u) { return __uint_as_float(u & 0xffff0000u); }

// Fused: x->bf16 convert (blocks 0..3124) | weight folds (3125..3380)
//        | init bcur slab cursors + zero pooled (3381..3414)
__global__ __launch_bounds__(256) void prep_kernel(
    const float* __restrict__ x, uint4* __restrict__ xb,
    const float* __restrict__ Wu1, const float* __restrict__ Wm1,
    const float* __restrict__ bm1, short* __restrict__ Wcatf1, float* __restrict__ c1,
    const float* __restrict__ Wu2, const float* __restrict__ Wm2,
    const float* __restrict__ bm2, short* __restrict__ Wcatf2, float* __restrict__ c2,
    int* __restrict__ bcur, float* __restrict__ pooled) {
    int bid = blockIdx.x, t = threadIdx.x;
    if (bid < 3125) {
        int i = bid * 256 + t;
        if (i < 800000) {
            const float4* p = (const float4*)(x + (size_t)i * 8);
            float4 f0 = p[0], f1 = p[1];
            uint4 r;
            r.x = ((unsigned)f2bfu(f0.y) << 16) | f2bfu(f0.x);
            r.y = ((unsigned)f2bfu(f0.w) << 16) | f2bfu(f0.z);
            r.z = ((unsigned)f2bfu(f1.y) << 16) | f2bfu(f1.x);
            r.w = ((unsigned)f2bfu(f1.w) << 16) | f2bfu(f1.z);
            xb[i] = r;
        }
    } else if (bid < 3381) {
        int lb = bid - 3125;
        int layer = lb >> 7;
        int o = lb & 127;
        int k = t;  // 0..255
        const float* Wu = layer ? Wu2 : Wu1;
        const float* Wm = layer ? Wm2 : Wm1;
        const float* bm = layer ? bm2 : bm1;
        short* Wcatf = layer ? Wcatf2 : Wcatf1;
        float* cvec = layer ? c2 : c1;
        float val;
        if (k < 128) {
            val = Wu[o * 256 + k];
        } else {
            int kk = k - 128;
            float s = 0.f;
            for (int j = 0; j < 128; ++j) s += Wu[o * 256 + 128 + j] * Wm[j * 128 + kk];
            val = s;
        }
        Wcatf[(((k >> 3) * 128) + o) * 8 + (k & 7)] = f2bf(val);
        if (k == 0) {
            float cs = 0.f;
            for (int j = 0; j < 128; ++j) cs += Wu[o * 256 + 128 + j] * bm[j];
            cvec[o] = cs;
        }
    } else {
        int i = (bid - 3381) * 256 + t;
        if (i < 512) bcur[i] = i * SLAB;            // slab cursor = slab base
        else if (i < 512 + 8192) pooled[i - 512] = 0.f;
    }
}

// pass A: bin edges by bucket through LDS; slab-allocate runs via bcur atomics.
__global__ __launch_bounds__(1024) void binA_kernel(const int* __restrict__ row,
                                                    const int* __restrict__ col,
                                                    int* __restrict__ bcur,
                                                    unsigned* __restrict__ ebin, int E) {
    __shared__ int lcur[NBUCK];
    __shared__ int lscan[NBUCK];
    __shared__ int gbase[NBUCK];
    __shared__ int sscan[512];
    __shared__ unsigned stage[8192];
    int t = threadIdx.x;
    for (int i = t; i < NBUCK; i += 1024) lcur[i] = 0;
    __syncthreads();
    int e0 = blockIdx.x * 8192;
    unsigned pv[8];
    int pb[8], pr[8];
#pragma unroll
    for (int k = 0; k < 8; ++k) {
        int e = e0 + k * 1024 + t;
        if (e < E) {
            int r = row[e], c = col[e];
            pv[k] = ((unsigned)r << 16) | (unsigned)c;
            pb[k] = r >> 7;
            pr[k] = atomicAdd(&lcur[pb[k]], 1);
        } else {
            pb[k] = -1;
        }
    }
    __syncthreads();
    if (t < 512) sscan[t] = (t < NBUCK) ? lcur[t] : 0;
    __syncthreads();
    for (int o = 1; o < 512; o <<= 1) {
        int a = 0;
        if (t < 512 && t >= o) a = sscan[t - o];
        __syncthreads();
        if (t < 512) sscan[t] += a;
        __syncthreads();
    }
    if (t < NBUCK) lscan[t] = sscan[t] - lcur[t];
    __syncthreads();
    for (int i = t; i < NBUCK; i += 1024) {
        int c = lcur[i];
        gbase[i] = c ? atomicAdd(&bcur[i], c) : 0;
    }
#pragma unroll
    for (int k = 0; k < 8; ++k)
        if (pb[k] >= 0) stage[lscan[pb[k]] + pr[k]] = pv[k];
    __syncthreads();
    int total = E - e0;
    if (total > 8192) total = 8192;
    for (int idx = t; idx < total; idx += 1024) {
        unsigned v = stage[idx];
        int b = v >> 23;
        ebin[gbase[b] + (idx - lscan[b])] = v;
    }
}

// pass B: per bucket slab, build csr segment (ushort) + hist + off entirely in LDS
__global__ __launch_bounds__(256) void binB_kernel(const unsigned* __restrict__ ebin,
                                                   const int* __restrict__ bcur,
                                                   unsigned short* __restrict__ csr,
                                                   int* __restrict__ hist,
                                                   int* __restrict__ off, int N) {
    __shared__ int lcnt[128];
    __shared__ int loff[128];
    __shared__ int lcur2[128];
    __shared__ int sscan[128];
    __shared__ unsigned short stage[SLAB];
    int b = blockIdx.x, t = threadIdx.x;
    int base = b * SLAB;
    int n = bcur[b] - base;
    if (n > SLAB) n = SLAB;  // safety clamp
    if (t < 128) lcnt[t] = 0;
    __syncthreads();
    for (int idx = t; idx < n; idx += 256) {
        unsigned v = ebin[base + idx];
        atomicAdd(&lcnt[(v >> 16) & 127], 1);
    }
    __syncthreads();
    if (t < 128) sscan[t] = lcnt[t];
    __syncthreads();
    for (int o = 1; o < 128; o <<= 1) {
        int a = 0;
        if (t < 128 && t >= o) a = sscan[t - o];
        __syncthreads();
        if (t < 128) sscan[t] += a;
        __syncthreads();
    }
    if (t < 128) {
        loff[t] = sscan[t] - lcnt[t];
        lcur2[t] = sscan[t] - lcnt[t];
    }
    __syncthreads();
    for (int idx = t; idx < n; idx += 256) {
        unsigned v = ebin[base + idx];
        int lr = (v >> 16) & 127;
        int pos = atomicAdd(&lcur2[lr], 1);
        stage[pos] = (unsigned short)(v & 0xffffu);
    }
    __syncthreads();
    for (int idx = t; idx < n; idx += 256) csr[base + idx] = stage[idx];
    int r0 = b * 128;
    if (t < 128 && r0 + t < N) {
        hist[r0 + t] = lcnt[t];
        off[r0 + t] = base + loff[t];
    }
}

// agg[n] = sum of src rows (bf16) over csr neighbors. One wave per node.
// 16-lane group strides its own neighbors; group lanes share one csr[i] (HW broadcast).
__global__ __launch_bounds__(256) void gather_kernel(const unsigned short* __restrict__ src,
                                                     const int* __restrict__ off,
                                                     const int* __restrict__ hist,
                                                     const unsigned short* __restrict__ csr,
                                                     unsigned int* __restrict__ aggb, int N) {
    int wave = threadIdx.x >> 6, lane = threadIdx.x & 63;
    int n = blockIdx.x * 4 + wave;
    if (n >= N) return;
    int s = off[n];
    int e = s + hist[n];
    int grp = lane >> 4, sub = lane & 15;
    float a0 = 0.f, a1 = 0.f, a2 = 0.f, a3 = 0.f, a4 = 0.f, a5 = 0.f, a6 = 0.f, a7 = 0.f;
#pragma unroll 4
    for (int i = s + grp; i < e; i += 4) {
        int c = csr[i];
        uint4 v = *(const uint4*)(src + (size_t)c * 128 + sub * 8);
        a0 += bflo(v.x); a1 += bfhi(v.x);
        a2 += bflo(v.y); a3 += bfhi(v.y);
        a4 += bflo(v.z); a5 += bfhi(v.z);
        a6 += bflo(v.w); a7 += bfhi(v.w);
    }
#pragma unroll
    for (int mk = 16; mk <= 32; mk <<= 1) {
        a0 += __shfl_xor(a0, mk); a1 += __shfl_xor(a1, mk);
        a2 += __shfl_xor(a2, mk); a3 += __shfl_xor(a3, mk);
        a4 += __shfl_xor(a4, mk); a5 += __shfl_xor(a5, mk);
        a6 += __shfl_xor(a6, mk); a7 += __shfl_xor(a7, mk);
    }
    if (grp == 0) {
        uint4 r;
        r.x = ((unsigned)f2bfu(a1) << 16) | f2bfu(a0);
        r.y = ((unsigned)f2bfu(a3) << 16) | f2bfu(a2);
        r.z = ((unsigned)f2bfu(a5) << 16) | f2bfu(a4);
        r.w = ((unsigned)f2bfu(a7) << 16) | f2bfu(a6);
        ((uint4*)aggb)[(size_t)n * 16 + sub] = r;
    }
}

// h = relu([xin|agg] @ Wcat^T + deg*c + bu).  512 thr = 8 waves; block = 256 nodes.
// B staged in LDS; xin A-fragments prefetched into regs under the staging drain.
template <int POOL>
__global__ __launch_bounds__(512, 4) void update_kernel(
    const void* __restrict__ xin_, const unsigned int* __restrict__ aggb,
    const int* __restrict__ hist, const float* __restrict__ cvec,
    const float* __restrict__ bupd, const short* __restrict__ Wcatf,
    unsigned int* __restrict__ houtb, float* __restrict__ pooled,
    const int* __restrict__ batch, int N) {
    __shared__ short lds_s[32768];  // 64KB
    __shared__ int batch_sh[256];
    const int tid = threadIdx.x;
    const int wave = tid >> 6, lane = tid & 63;
    const int l31 = lane & 31, hi = lane >> 5;

    {  // stage B: linear 64KB copy
        const uint4* g = (const uint4*)Wcatf;
        uint4* l4 = (uint4*)lds_s;
#pragma unroll
        for (int j = 0; j < 8; ++j) l4[j * 512 + tid] = g[j * 512 + tid];
    }

    const int m0 = blockIdx.x * 256 + wave * 32;
    int nr = m0 + l31;
    if (nr >= N) nr = N - 1;
    // prefetch xin A-fragments; latency hides under the staging vmcnt drain + barrier
    short8 ax[8];
#pragma unroll
    for (int s = 0; s < 8; ++s)
        ax[s] = *(const short8*)((const short*)xin_ + (size_t)nr * 128 + s * 16 + hi * 8);
    if (POOL && tid < 256)
        batch_sh[tid] = (blockIdx.x * 256 + tid < N) ? batch[blockIdx.x * 256 + tid] : 0;
    __syncthreads();

    f32x16 acc[4] = {};
#pragma unroll
    for (int step = 0; step < 16; ++step) {
        short8 a;
        if (step < 8) {
            a = ax[step];
        } else {
            a = *(const short8*)((const short*)aggb + (size_t)nr * 128 + (step - 8) * 16 + hi * 8);
        }
#pragma unroll
        for (int ct = 0; ct < 4; ++ct) {
            const short8 b = *(const short8*)(lds_s + (((step * 2 + hi) * 128) + ct * 32 + l31) * 8);
            acc[ct] = __builtin_amdgcn_mfma_f32_32x32x16_bf16(a, b, acc[ct], 0, 0, 0);
        }
    }
    __syncthreads();  // B dead; LDS becomes transpose buffer

    float dv[16];
#pragma unroll
    for (int r = 0; r < 16; ++r) {
        int row = (r & 3) + 8 * (r >> 2) + 4 * hi;
        int node = m0 + row;
        if (node >= N) node = N - 1;
        dv[r] = (float)hist[node];
    }
    short* tp = lds_s + wave * 4096;  // [32][128] bf16 per wave
#pragma unroll
    for (int ct = 0; ct < 4; ++ct) {
        int o = ct * 32 + l31;
        float co = cvec[o], bo = bupd[o];
#pragma unroll
        for (int r = 0; r < 16; ++r) {
            int row = (r & 3) + 8 * (r >> 2) + 4 * hi;
            float v = fmaxf(acc[ct][r] + dv[r] * co + bo, 0.f);
            tp[row * 128 + o] = f2bf(v);
        }
    }
    __syncthreads();

    if (POOL == 0) {
        const uint4* l4 = (const uint4*)tp;
#pragma unroll
        for (int j = 0; j < 8; ++j) {
            int node = m0 + j * 4 + (lane >> 4);
            if (node < N)
                ((uint4*)houtb)[(size_t)m0 * 16 + j * 64 + lane] = l4[j * 64 + lane];
        }
    } else {
        // block-local segmented pool over sorted batch (batch staged in LDS)
        int c = tid & 127, seg = tid >> 7;
        int base = blockIdx.x * 256 + seg * 64;
        float s = 0.f;
        int gprev = -1;
        for (int i = 0; i < 64; ++i) {
            int node = base + i;
            if (node >= N) break;
            int g = batch_sh[seg * 64 + i];
            if (g != gprev) {
                if (gprev >= 0) atomicAdd(&pooled[gprev * 128 + c], s);
                s = 0.f;
                gprev = g;
            }
            unsigned u = (unsigned short)lds_s[(seg * 64 + i) * 128 + c];
            s += __uint_as_float(u << 16);
        }
        if (gprev >= 0) atomicAdd(&pooled[gprev * 128 + c], s);
    }
}

// out[g] = (pooled[g]/count(g)) @ Wcls^T + bcls; count via binary search on sorted batch
__global__ void final_kernel(const float* __restrict__ pooled, const int* __restrict__ batch,
                             const float* __restrict__ Wcls, const float* __restrict__ bcls,
                             float* __restrict__ out, int N) {
    __shared__ float sh[128];
    __shared__ int cntsh;
    int g = blockIdx.x;
    int t = threadIdx.x;
    if (t == 0) {
        int lo = 0, hi = N;
        while (lo < hi) { int mid = (lo + hi) >> 1; if (batch[mid] < g) lo = mid + 1; else hi = mid; }
        int start = lo;
        lo = 0; hi = N;
        while (lo < hi) { int mid = (lo + hi) >> 1; if (batch[mid] < g + 1) lo = mid + 1; else hi = mid; }
        cntsh = lo - start;
    }
    __syncthreads();
    float c = (cntsh > 0) ? (float)cntsh : 1.f;
    sh[t] = pooled[g * 128 + t] / c;
    __syncthreads();
    if (t < 10) {
        float s = bcls[t];
        for (int i = 0; i < 128; ++i) s += sh[i] * Wcls[t * 128 + i];
        out[g * 10 + t] = s;
    }
}

extern "C" void kernel_launch(void* const* d_in, const int* in_sizes, int n_in,
                              void* d_out, int out_size, void* d_ws, size_t ws_size,
                              hipStream_t stream) {
    const float* x = (const float*)d_in[0];
    const int* ei = (const int*)d_in[1];
    const int* batch = (const int*)d_in[2];
    const float* Wm1 = (const float*)d_in[3];
    const float* bm1 = (const float*)d_in[4];
    const float* Wu1 = (const float*)d_in[5];
    const float* bu1 = (const float*)d_in[6];
    const float* Wm2 = (const float*)d_in[7];
    const float* bm2 = (const float*)d_in[8];
    const float* Wu2 = (const float*)d_in[9];
    const float* bu2 = (const float*)d_in[10];
    const float* Wcls = (const float*)d_in[11];
    const float* bcls = (const float*)d_in[12];
    float* out = (float*)d_out;

    const int N = N_NODES, E = N_EDGES;
    const int* row = ei;
    const int* col = ei + E;
    const int EB = (E + 8191) / 8192;  // 98 binning blocks
    const int UB = (N + 255) / 256;    // 196 update blocks
    const int GB = (N + 3) / 4;        // 12500 gather blocks

    // workspace layout (int units from base)
    int* bcur = (int*)d_ws;                        // 512
    float* pooled = (float*)(bcur + 512);          // 8192
    int* hist = (int*)(pooled + 8192);             // 50000
    int* off = hist + 50000;                       // 50000
    unsigned* ebin = (unsigned*)(off + 50000);     // NBUCK*SLAB = 1,601,536
    unsigned short* csr = (unsigned short*)(ebin + NBUCK * SLAB);  // 1,601,536 ushorts
    unsigned* aggb = (unsigned*)(csr + NBUCK * SLAB);  // 3,200,000 (csr is even-sized)
    unsigned* h1b = aggb + 3200000;                // 3,200,000
    unsigned* xb = h1b + 3200000;                  // 3,200,000
    float* c1 = (float*)(xb + 3200000);            // 128
    float* c2 = c1 + 128;                          // 128
    short* Wcatf1 = (short*)(c2 + 128);            // 32768 shorts
    short* Wcatf2 = Wcatf1 + 32768;                // 32768 shorts

    prep_kernel<<<3415, 256, 0, stream>>>(x, (uint4*)xb, Wu1, Wm1, bm1, Wcatf1, c1,
                                          Wu2, Wm2, bm2, Wcatf2, c2, bcur, pooled);
    binA_kernel<<<EB, 1024, 0, stream>>>(row, col, bcur, ebin, E);
    binB_kernel<<<NBUCK, 256, 0, stream>>>(ebin, bcur, csr, hist, off, N);

    // layer 1
    gather_kernel<<<GB, 256, 0, stream>>>((const unsigned short*)xb, off, hist,
                                          csr, aggb, N);
    update_kernel<0><<<UB, 512, 0, stream>>>(xb, aggb, hist, c1, bu1, Wcatf1,
                                             h1b, nullptr, nullptr, N);
    // layer 2
    gather_kernel<<<GB, 256, 0, stream>>>((const unsigned short*)h1b, off, hist,
                                          csr, aggb, N);
    update_kernel<1><<<UB, 512, 0, stream>>>(h1b, aggb, hist, c2, bu2, Wcatf2,
                                             nullptr, pooled, batch, N);

    final_kernel<<<NUM_GRAPHS, 128, 0, stream>>>(pooled, batch, Wcls, bcls, out, N);
}